// Round 1
// baseline (202.790 us; speedup 1.0000x reference)
//
#include <hip/hip_runtime.h>

typedef __attribute__((ext_vector_type(8))) short short8;
typedef __attribute__((ext_vector_type(4))) float f32x4;
typedef unsigned short u16;
typedef unsigned int u32;

#define NNODES 65536
#define FDIM 128

__device__ __forceinline__ u16 f2bf(float f) {
    u32 u = __float_as_uint(f);
    u32 r = (u + 0x7fffu + ((u >> 16) & 1u)) >> 16;   // RNE
    return (u16)r;
}

// ---------- rowptr via binary search over sorted edge_row ----------
__global__ void rowptr_kernel(const int* __restrict__ erow, int* __restrict__ rowptr,
                              int n, int e) {
    int r = blockIdx.x * blockDim.x + threadIdx.x;
    if (r > n) return;
    int lo = 0, hi = e;
    while (lo < hi) {
        int mid = (lo + hi) >> 1;
        if (erow[mid] < r) lo = mid + 1; else hi = mid;
    }
    rowptr[r] = lo;
}

// ---------- x fp32 -> bf16 ----------
__global__ void cvt_x_kernel(const float* __restrict__ x, u16* __restrict__ xb, int total4) {
    int i = blockIdx.x * blockDim.x + threadIdx.x;
    if (i >= total4) return;
    float4 v = reinterpret_cast<const float4*>(x)[i];
    uint2 p;
    p.x = ((u32)f2bf(v.y) << 16) | f2bf(v.x);
    p.y = ((u32)f2bf(v.w) << 16) | f2bf(v.z);
    reinterpret_cast<uint2*>(xb)[i] = p;
}

// ---------- weight fp32 [K][NC] -> bf16 transposed [NC][K] ----------
__global__ void cvt_wT_kernel(const float* __restrict__ w, u16* __restrict__ wt,
                              int K, int NC) {
    int idx = blockIdx.x * blockDim.x + threadIdx.x;
    if (idx >= K * NC) return;
    int n = idx / K, k = idx - n * K;
    wt[idx] = f2bf(w[k * NC + n]);
}

// ---------- SpMM: y[r] = sum_e val*h[col], one wave per row ----------
// h, y: bf16 [N][128]. lane handles 2 features (4B packed).
__global__ void spmm_kernel(const u16* __restrict__ h, const int* __restrict__ rowptr,
                            const int* __restrict__ col, const float* __restrict__ val,
                            u16* __restrict__ y, int n) {
    int wid = (blockIdx.x * blockDim.x + threadIdx.x) >> 6;
    int lane = threadIdx.x & 63;
    if (wid >= n) return;
    int s = rowptr[wid], e = rowptr[wid + 1];
    float a0 = 0.f, a1 = 0.f;
    for (int i = s; i < e; ++i) {
        int c = col[i];
        float v = val[i];
        u32 u = *reinterpret_cast<const u32*>(h + (size_t)c * FDIM + lane * 2);
        float f0 = __uint_as_float(u << 16);
        float f1 = __uint_as_float(u & 0xffff0000u);
        a0 = fmaf(v, f0, a0);
        a1 = fmaf(v, f1, a1);
    }
    u32 pack = ((u32)f2bf(a1) << 16) | f2bf(a0);
    *reinterpret_cast<u32*>(y + (size_t)wid * FDIM + lane * 2) = pack;
}

// ---------- GEMM: out[M][NT*16] = A[M][128] @ W[128][NT*16] (W passed transposed) ----------
// B fragments for the whole weight held in registers (loaded once per wave).
// MFMA 16x16x32 bf16. A frag: lane holds A[r0 + (lane&15)][kstep*32 + (lane>>4)*8 + j].
// C/D: col = lane&15, row = (lane>>4)*4 + reg (verified layout).
template<int NT, bool RELU, bool OUT_BF16>
__global__ void gemm_kernel(const u16* __restrict__ A, const u16* __restrict__ WT,
                            void* __restrict__ out, int M) {
    const int lane = threadIdx.x & 63;
    const int dn = lane & 15;
    const int kg = lane >> 4;

    short8 bf[NT][4];
#pragma unroll
    for (int nt = 0; nt < NT; ++nt)
#pragma unroll
        for (int s = 0; s < 4; ++s)
            bf[nt][s] = *reinterpret_cast<const short8*>(
                &WT[(size_t)(nt * 16 + dn) * 128 + s * 32 + kg * 8]);

    const int nwaves = (gridDim.x * blockDim.x) >> 6;
    const int gwave  = (blockIdx.x * blockDim.x + threadIdx.x) >> 6;
    const int nchunk = M >> 4;

    for (int ch = gwave; ch < nchunk; ch += nwaves) {
        const int r0 = ch << 4;
        f32x4 acc[NT];
#pragma unroll
        for (int nt = 0; nt < NT; ++nt) acc[nt] = (f32x4){0.f, 0.f, 0.f, 0.f};

#pragma unroll
        for (int s = 0; s < 4; ++s) {
            short8 a = *reinterpret_cast<const short8*>(
                &A[(size_t)(r0 + dn) * 128 + s * 32 + kg * 8]);
#pragma unroll
            for (int nt = 0; nt < NT; ++nt)
                acc[nt] = __builtin_amdgcn_mfma_f32_16x16x32_bf16(a, bf[nt][s], acc[nt], 0, 0, 0);
        }

#pragma unroll
        for (int nt = 0; nt < NT; ++nt) {
#pragma unroll
            for (int i = 0; i < 4; ++i) {
                float v = acc[nt][i];
                if (RELU) v = fmaxf(v, 0.f);
                int row = r0 + kg * 4 + i;
                int c   = nt * 16 + dn;
                if (OUT_BF16)
                    ((u16*)out)[(size_t)row * (NT * 16) + c] = f2bf(v);
                else
                    ((float*)out)[(size_t)row * (NT * 16) + c] = v;
            }
        }
    }
}

extern "C" void kernel_launch(void* const* d_in, const int* in_sizes, int n_in,
                              void* d_out, int out_size, void* d_ws, size_t ws_size,
                              hipStream_t stream) {
    const float* x    = (const float*)d_in[0];
    const float* w1   = (const float*)d_in[1];
    const float* w2   = (const float*)d_in[2];
    const float* w3   = (const float*)d_in[3];
    const int*   erow = (const int*)d_in[4];
    const int*   ecol = (const int*)d_in[5];
    const float* eval = (const float*)d_in[6];
    float* out = (float*)d_out;

    const int N = in_sizes[0] / FDIM;
    const int E = in_sizes[4];

    char* ws = (char*)d_ws;
    int* rowptr = (int*)ws;                                  // (N+1)*4 = 256KB+4
    u16* wt1 = (u16*)(ws + (512 << 10));                     // 32KB
    u16* wt2 = wt1 + 128 * 128;                              // 32KB
    u16* wt3 = wt2 + 128 * 128;                              // 16KB
    u16* ybuf = (u16*)(ws + (1 << 20));                      // 16MB bf16 [N][128]
    u16* hbuf = (u16*)(ws + (18u << 20));                    // 16MB bf16 [N][128]

    // 1. CSR rowptr
    rowptr_kernel<<<(N + 1 + 255) / 256, 256, 0, stream>>>(erow, rowptr, N, E);
    // 2. weights -> bf16 transposed
    cvt_wT_kernel<<<(128 * 128 + 255) / 256, 256, 0, stream>>>(w1, wt1, 128, 128);
    cvt_wT_kernel<<<(128 * 128 + 255) / 256, 256, 0, stream>>>(w2, wt2, 128, 128);
    cvt_wT_kernel<<<(64 * 128 + 255) / 256, 256, 0, stream>>>(w3, wt3, 128, 64);
    // 3. x -> bf16 (staged in hbuf; consumed before gemm1 overwrites it)
    cvt_x_kernel<<<(N * FDIM / 4 + 255) / 256, 256, 0, stream>>>(x, hbuf, N * FDIM / 4);
    // 4. y = A @ x
    spmm_kernel<<<N / 4, 256, 0, stream>>>(hbuf, rowptr, ecol, eval, ybuf, N);
    // 5. h1 = relu(y @ w1)
    gemm_kernel<8, true, true><<<512, 256, 0, stream>>>(ybuf, wt1, hbuf, N);
    // 6. y = A @ h1
    spmm_kernel<<<N / 4, 256, 0, stream>>>(hbuf, rowptr, ecol, eval, ybuf, N);
    // 7. h2 = relu(y @ w2)
    gemm_kernel<8, true, true><<<512, 256, 0, stream>>>(ybuf, wt2, hbuf, N);
    // 8. out = h2 @ w3 (fp32)
    gemm_kernel<4, false, false><<<1024, 256, 0, stream>>>(hbuf, wt3, (void*)out, N);
}

// Round 2
// 144.152 us; speedup vs baseline: 1.4068x; 1.4068x over previous
//
#include <hip/hip_runtime.h>

typedef __attribute__((ext_vector_type(8))) short short8;
typedef __attribute__((ext_vector_type(4))) float f32x4;
typedef unsigned short u16;
typedef unsigned int u32;

#define NNODES 65536
#define FDIM 128

__device__ __forceinline__ u16 f2bf(float f) {
    u32 u = __float_as_uint(f);
    u32 r = (u + 0x7fffu + ((u >> 16) & 1u)) >> 16;   // RNE
    return (u16)r;
}

// ---------- rowptr via binary search over sorted edge_row ----------
__global__ void rowptr_kernel(const int* __restrict__ erow, int* __restrict__ rowptr,
                              int n, int e) {
    int r = blockIdx.x * blockDim.x + threadIdx.x;
    if (r > n) return;
    int lo = 0, hi = e;
    while (lo < hi) {
        int mid = (lo + hi) >> 1;
        if (erow[mid] < r) lo = mid + 1; else hi = mid;
    }
    rowptr[r] = lo;
}

// ---------- x fp32 -> bf16 ----------
__global__ void cvt_x_kernel(const float* __restrict__ x, u16* __restrict__ xb, int total4) {
    int i = blockIdx.x * blockDim.x + threadIdx.x;
    if (i >= total4) return;
    float4 v = reinterpret_cast<const float4*>(x)[i];
    uint2 p;
    p.x = ((u32)f2bf(v.y) << 16) | f2bf(v.x);
    p.y = ((u32)f2bf(v.w) << 16) | f2bf(v.z);
    reinterpret_cast<uint2*>(xb)[i] = p;
}

// ---------- weight fp32 [K][NC] -> bf16 transposed [NC][K] ----------
__global__ void cvt_wT_kernel(const float* __restrict__ w, u16* __restrict__ wt,
                              int K, int NC) {
    int idx = blockIdx.x * blockDim.x + threadIdx.x;
    if (idx >= K * NC) return;
    int n = idx / K, k = idx - n * K;
    wt[idx] = f2bf(w[k * NC + n]);
}

// ---------- SpMM v2: one wave per row, 4 edges in flight ----------
// lane = (slot = lane>>4 -> edge parity, fg = lane&15 -> features fg*8..fg*8+7).
// Each lane gathers 16B of its slot's edge row; col/val for the next chunk are
// prefetched past the current gather. Butterfly-reduce across slots, then a
// fully-coalesced 256B/row store (each lane writes the 4B word of its slot).
__global__ void spmm_kernel(const u16* __restrict__ h, const int* __restrict__ rowptr,
                            const int* __restrict__ col, const float* __restrict__ val,
                            u16* __restrict__ y, int n) {
    int wid = (blockIdx.x * blockDim.x + threadIdx.x) >> 6;
    int lane = threadIdx.x & 63;
    if (wid >= n) return;
    const int slot = lane >> 4;
    const int fg = lane & 15;
    int s = rowptr[wid], e = rowptr[wid + 1];

    float acc[8];
#pragma unroll
    for (int j = 0; j < 8; ++j) acc[j] = 0.f;

    int i = s + slot;
    int c = 0; float v = 0.f;
    if (i < e) { c = col[i]; v = val[i]; }
    while (i < e) {
        int inext = i + 4;
        int cn = 0; float vn = 0.f;
        if (inext < e) { cn = col[inext]; vn = val[inext]; }   // prefetch next chunk
        short8 hv = *reinterpret_cast<const short8*>(h + (size_t)c * FDIM + fg * 8);
#pragma unroll
        for (int j = 0; j < 8; ++j) {
            float f = __uint_as_float(((u32)(u16)hv[j]) << 16);
            acc[j] = fmaf(v, f, acc[j]);
        }
        i = inext; c = cn; v = vn;
    }

#pragma unroll
    for (int m = 16; m <= 32; m <<= 1)
#pragma unroll
        for (int j = 0; j < 8; ++j)
            acc[j] += __shfl_xor(acc[j], m, 64);

    // lane writes the u32 (= 2 features) of its slot within feature-group fg
    float a0 = 0.f, a1 = 0.f;
#pragma unroll
    for (int ss = 0; ss < 4; ++ss)
        if (slot == ss) { a0 = acc[ss * 2]; a1 = acc[ss * 2 + 1]; }
    u32 pack = ((u32)f2bf(a1) << 16) | f2bf(a0);
    *reinterpret_cast<u32*>(y + (size_t)wid * FDIM + fg * 8 + slot * 2) = pack;
}

// ---------- GEMM: out[M][NT*16] = A[M][128] @ W[128][NT*16] (W passed transposed) ----------
template<int NT, bool RELU, bool OUT_BF16>
__global__ void gemm_kernel(const u16* __restrict__ A, const u16* __restrict__ WT,
                            void* __restrict__ out, int M) {
    const int lane = threadIdx.x & 63;
    const int dn = lane & 15;
    const int kg = lane >> 4;

    short8 bf[NT][4];
#pragma unroll
    for (int nt = 0; nt < NT; ++nt)
#pragma unroll
        for (int s = 0; s < 4; ++s)
            bf[nt][s] = *reinterpret_cast<const short8*>(
                &WT[(size_t)(nt * 16 + dn) * 128 + s * 32 + kg * 8]);

    const int nwaves = (gridDim.x * blockDim.x) >> 6;
    const int gwave  = (blockIdx.x * blockDim.x + threadIdx.x) >> 6;
    const int nchunk = M >> 4;

    for (int ch = gwave; ch < nchunk; ch += nwaves) {
        const int r0 = ch << 4;
        f32x4 acc[NT];
#pragma unroll
        for (int nt = 0; nt < NT; ++nt) acc[nt] = (f32x4){0.f, 0.f, 0.f, 0.f};

#pragma unroll
        for (int s = 0; s < 4; ++s) {
            short8 a = *reinterpret_cast<const short8*>(
                &A[(size_t)(r0 + dn) * 128 + s * 32 + kg * 8]);
#pragma unroll
            for (int nt = 0; nt < NT; ++nt)
                acc[nt] = __builtin_amdgcn_mfma_f32_16x16x32_bf16(a, bf[nt][s], acc[nt], 0, 0, 0);
        }

#pragma unroll
        for (int nt = 0; nt < NT; ++nt) {
#pragma unroll
            for (int i = 0; i < 4; ++i) {
                float v = acc[nt][i];
                if (RELU) v = fmaxf(v, 0.f);
                int row = r0 + kg * 4 + i;
                int c   = nt * 16 + dn;
                if (OUT_BF16)
                    ((u16*)out)[(size_t)row * (NT * 16) + c] = f2bf(v);
                else
                    ((float*)out)[(size_t)row * (NT * 16) + c] = v;
            }
        }
    }
}

extern "C" void kernel_launch(void* const* d_in, const int* in_sizes, int n_in,
                              void* d_out, int out_size, void* d_ws, size_t ws_size,
                              hipStream_t stream) {
    const float* x    = (const float*)d_in[0];
    const float* w1   = (const float*)d_in[1];
    const float* w2   = (const float*)d_in[2];
    const float* w3   = (const float*)d_in[3];
    const int*   erow = (const int*)d_in[4];
    const int*   ecol = (const int*)d_in[5];
    const float* eval = (const float*)d_in[6];
    float* out = (float*)d_out;

    const int N = in_sizes[0] / FDIM;
    const int E = in_sizes[4];

    char* ws = (char*)d_ws;
    int* rowptr = (int*)ws;                                  // (N+1)*4 = 256KB+4
    u16* wt1 = (u16*)(ws + (512 << 10));                     // 32KB
    u16* wt2 = wt1 + 128 * 128;                              // 32KB
    u16* wt3 = wt2 + 128 * 128;                              // 16KB
    u16* ybuf = (u16*)(ws + (1 << 20));                      // 16MB bf16 [N][128]
    u16* hbuf = (u16*)(ws + (18u << 20));                    // 16MB bf16 [N][128]

    // 1. CSR rowptr
    rowptr_kernel<<<(N + 1 + 255) / 256, 256, 0, stream>>>(erow, rowptr, N, E);
    // 2. weights -> bf16 transposed
    cvt_wT_kernel<<<(128 * 128 + 255) / 256, 256, 0, stream>>>(w1, wt1, 128, 128);
    cvt_wT_kernel<<<(128 * 128 + 255) / 256, 256, 0, stream>>>(w2, wt2, 128, 128);
    cvt_wT_kernel<<<(64 * 128 + 255) / 256, 256, 0, stream>>>(w3, wt3, 128, 64);
    // 3. x -> bf16 (staged in hbuf; consumed before gemm1 overwrites it)
    cvt_x_kernel<<<(N * FDIM / 4 + 255) / 256, 256, 0, stream>>>(x, hbuf, N * FDIM / 4);
    // 4. y = A @ x
    spmm_kernel<<<N / 4, 256, 0, stream>>>(hbuf, rowptr, ecol, eval, ybuf, N);
    // 5. h1 = relu(y @ w1)
    gemm_kernel<8, true, true><<<512, 256, 0, stream>>>(ybuf, wt1, hbuf, N);
    // 6. y = A @ h1
    spmm_kernel<<<N / 4, 256, 0, stream>>>(hbuf, rowptr, ecol, eval, ybuf, N);
    // 7. h2 = relu(y @ w2)
    gemm_kernel<8, true, true><<<512, 256, 0, stream>>>(ybuf, wt2, hbuf, N);
    // 8. out = h2 @ w3 (fp32)
    gemm_kernel<4, false, false><<<1024, 256, 0, stream>>>(hbuf, wt3, (void*)out, N);
}